// Round 16
// baseline (569.460 us; speedup 1.0000x reference)
//
#include <hip/hip_runtime.h>

typedef __attribute__((ext_vector_type(8))) short short8v;
typedef __attribute__((ext_vector_type(4))) float f32x4;
typedef __attribute__((ext_vector_type(4))) unsigned int uint4v;

#define GLOBAL_AS(p) ((const __attribute__((address_space(1))) void*)(p))
#define LDS_AS(p)    ((__attribute__((address_space(3))) void*)(p))
#define WAITV(n) asm volatile("s_waitcnt vmcnt(" #n ")" ::: "memory")
#define BARRIER() __builtin_amdgcn_s_barrier()

__device__ __forceinline__ unsigned short f2bf(float f) {
  unsigned int u = __builtin_bit_cast(unsigned int, f);
  u += 0x7fffu + ((u >> 16) & 1u);
  return (unsigned short)(u >> 16);
}
__device__ __forceinline__ float bf2f(unsigned short u) {
  unsigned int x = ((unsigned int)u) << 16;
  return __builtin_bit_cast(float, x);
}

// ---------------------------------------------------------------------------
// Merged prep: [0,12288) weight transposes fp32[K,N]->bf16[N,K];
// [12288,12316) bias concat; [12316,28700) x fp32->bf16 (XCD-aligned rows).
__global__ __launch_bounds__(256) void prep_kernel(
    const float* __restrict__ x,
    const float* __restrict__ Wq, const float* __restrict__ Wo,
    const float* __restrict__ Wd_k, const float* __restrict__ Wd_v,
    const float* __restrict__ Wu_k, const float* __restrict__ Wu_v,
    const float* __restrict__ bd_k, const float* __restrict__ bd_v,
    const float* __restrict__ bq, const float* __restrict__ bu_k,
    const float* __restrict__ bu_v,
    unsigned short* __restrict__ w1t, unsigned short* __restrict__ w2t,
    unsigned short* __restrict__ w3t, float* __restrict__ b1,
    float* __restrict__ b2, unsigned short* __restrict__ xb) {
  int b = blockIdx.x;
  if (b >= 12316) {  // ---- x fp32 -> bf16
    const int o = b - 12316;
    const size_t row = (size_t)((o & 7) * 2048 + (o >> 3));
    size_t i = row * 2048 + threadIdx.x * 8;
    f32x4 v0 = *(const f32x4*)(x + i);
    f32x4 v1 = *(const f32x4*)(x + i + 4);
    union U8 { uint4v v; unsigned short us[8]; } o8;
    o8.us[0] = f2bf(v0.x); o8.us[1] = f2bf(v0.y); o8.us[2] = f2bf(v0.z); o8.us[3] = f2bf(v0.w);
    o8.us[4] = f2bf(v1.x); o8.us[5] = f2bf(v1.y); o8.us[6] = f2bf(v1.z); o8.us[7] = f2bf(v1.w);
    *(uint4v*)(xb + i) = o8.v;
    return;
  }
  if (b >= 12288) {  // ---- bias concat
    int i = (b - 12288) * 256 + threadIdx.x;
    if (i < 512) b1[i] = bd_k[i];
    else if (i < 1024) b1[i] = bd_v[i - 512];
    else if (i < 3072) b1[i] = bq[i - 1024];
    else if (i < 5120) b2[i - 3072] = bu_k[i - 3072];
    else if (i < 7168) b2[i - 3072] = bu_v[i - 5120];
    return;
  }
  // ---- weight transpose (verified 32x32 LDS-bounce)
  const float* src; unsigned short* dst; int K, N, ntx;
  if (b < 4096)      { src = Wq;   dst = w1t + 1024 * 2048; K = 2048; N = 2048; ntx = 64; }
  else if (b < 8192) { src = Wo;   dst = w3t;               K = 2048; N = 2048; ntx = 64; b -= 4096; }
  else if (b < 9216) { src = Wd_k; dst = w1t;               K = 2048; N = 512;  ntx = 16; b -= 8192; }
  else if (b < 10240){ src = Wd_v; dst = w1t + 512 * 2048;  K = 2048; N = 512;  ntx = 16; b -= 9216; }
  else if (b < 11264){ src = Wu_k; dst = w2t;               K = 512;  N = 2048; ntx = 64; b -= 10240; }
  else               { src = Wu_v; dst = w2t + 2048 * 512;  K = 512;  N = 2048; ntx = 64; b -= 11264; }
  __shared__ float tile[32][33];
  const int bx = b % ntx, by = b / ntx;
  const int tx = threadIdx.x & 31, ty = threadIdx.x >> 5;
  const int k0 = by * 32, n0 = bx * 32;
#pragma unroll
  for (int i = 0; i < 32; i += 8)
    tile[ty + i][tx] = src[(size_t)(k0 + ty + i) * N + n0 + tx];
  __syncthreads();
#pragma unroll
  for (int i = 0; i < 32; i += 8)
    dst[(size_t)(n0 + ty + i) * K + k0 + tx] = f2bf(tile[tx][ty + i]);
}

// ---------------------------------------------------------------------------
// 256x256x64 bf16 GEMM, 512 thr / 8 waves (2Mx4N), per-wave 128x64.
// R13 quadrant schedule WITHOUT manual lgkm drains: B frags (8xb128) read
// once at q0 and held in regs for all 4 phases; A streams 4xb128/phase.
// Plain-C++ ds_reads -> compiler inserts minimal counted lgkmcnt before each
// MFMA use (m97 evidence); the manual lgkmcnt(0) in R13 added ~560cy/tile of
// dead drain (the measured 41% vs ~55% ceiling). Raw barriers retained:
// every LDS region has >=2 barriers between last read issue and overwrite
// (B: read q0 / overwritten q2; A quarters: read by q3 / overwritten next
// tile q0-q1), so reads (~120cy) can't race gload_lds writes (>=200cy).
// Counted vmcnt(4) once per tile at q3.
template <int OUT_BF16>
__global__ __launch_bounds__(512, 2) void gemm_bt(
    const unsigned short* __restrict__ A, int lda, int nsplit_col, int acol_off,
    const unsigned short* __restrict__ Bt, int ldb,
    const float* __restrict__ bias, void* __restrict__ Cp, int ldc,
    int K, int ntn) {
  __shared__ unsigned short lds[2][2][256 * 64];  // [dbuf][A|B] 128KB
  const int t = threadIdx.x;
  const int lane = t & 63, wave = t >> 6;

  const int qx = gridDim.x >> 3;
  const int bid = (blockIdx.x & 7) * qx + (blockIdx.x >> 3);
  const int bm = (bid / ntn) * 256;
  const int bn = (bid % ntn) * 256;
  const unsigned short* Ab = A + (bn >= nsplit_col ? acol_off : 0);

  const int wr = wave >> 2, wc = wave & 3;
  const int g = lane >> 4, r = lane & 15;
  const int c16_0 = (g ^ (r & 7)) << 3;
  const int c16_1 = ((4 + g) ^ (r & 7)) << 3;
  const int NT = K >> 6;

  f32x4 acc[8][4];
#pragma unroll
  for (int i = 0; i < 8; ++i)
#pragma unroll
    for (int j = 0; j < 4; ++j) acc[i][j] = (f32x4){0.f, 0.f, 0.f, 0.f};

  const int trow = t >> 3;
  const int jsrc = (t & 7) ^ (trow & 7);
  const unsigned short* aptr = Ab + (size_t)(bm + trow) * lda + (jsrc << 3);
  const unsigned short* bptr = Bt + (size_t)(bn + trow) * ldb + (jsrc << 3);
  const int wbase = wave * 512;

  auto stageA = [&](int kt, int h2) {
    unsigned short* dst = &lds[kt & 1][0][h2 * 8192 + wbase];
    const unsigned short* src = aptr + (size_t)(h2 * 128) * lda + kt * 64;
    __builtin_amdgcn_global_load_lds(GLOBAL_AS(src), LDS_AS(dst), 16, 0, 0);
    __builtin_amdgcn_global_load_lds(GLOBAL_AS(src + (size_t)64 * lda),
                                     LDS_AS(dst + 4096), 16, 0, 0);
  };
  auto stageB = [&](int kt, int h2) {
    unsigned short* dst = &lds[kt & 1][1][h2 * 8192 + wbase];
    const unsigned short* src = bptr + (size_t)(h2 * 128) * ldb + kt * 64;
    __builtin_amdgcn_global_load_lds(GLOBAL_AS(src), LDS_AS(dst), 16, 0, 0);
    __builtin_amdgcn_global_load_lds(GLOBAL_AS(src + (size_t)64 * ldb),
                                     LDS_AS(dst + 4096), 16, 0, 0);
  };

  short8v bq[4][2], aq[2][2];
  auto readB = [&](const unsigned short* lb) {
#pragma unroll
    for (int ni = 0; ni < 4; ++ni) {
      bq[ni][0] = *(const short8v*)&lb[(wc * 64 + ni * 16 + r) * 64 + c16_0];
      bq[ni][1] = *(const short8v*)&lb[(wc * 64 + ni * 16 + r) * 64 + c16_1];
    }
  };
  auto readA = [&](const unsigned short* la, int q) {
#pragma unroll
    for (int mi = 0; mi < 2; ++mi) {
      aq[mi][0] = *(const short8v*)&la[(wr * 128 + q * 32 + mi * 16 + r) * 64 + c16_0];
      aq[mi][1] = *(const short8v*)&la[(wr * 128 + q * 32 + mi * 16 + r) * 64 + c16_1];
    }
  };
  auto MF = [&](int q) {
    __builtin_amdgcn_s_setprio(1);
#pragma unroll
    for (int mi = 0; mi < 2; ++mi)
#pragma unroll
      for (int ni = 0; ni < 4; ++ni)
#pragma unroll
        for (int ks = 0; ks < 2; ++ks)
          acc[q * 2 + mi][ni] = __builtin_amdgcn_mfma_f32_16x16x32_bf16(
              aq[mi][ks], bq[ni][ks], acc[q * 2 + mi][ni], 0, 0, 0);
    __builtin_amdgcn_s_setprio(0);
  };

  // prologue: tiles 0,1 fully staged; drain tile0, keep tile1's 8 in flight.
  stageA(0, 0); stageA(0, 1); stageB(0, 0); stageB(0, 1);
  stageA(1, 0); stageA(1, 1); stageB(1, 0); stageB(1, 1);
  WAITV(8);
  BARRIER();

  for (int t2 = 0; t2 < NT; t2 += 2) {
    const bool sA1 = (t2 > 0);
    const bool sN = (t2 + 2 < NT);
    const unsigned short* la0 = lds[0][0];
    const unsigned short* lb0 = lds[0][1];
    const unsigned short* la1 = lds[1][0];
    const unsigned short* lb1 = lds[1][1];

    // ---------- tile t2 (dbuf 0) ----------
    readB(lb0); readA(la0, 0);
    if (sA1) stageA(t2 + 1, 0);
    BARRIER();
    MF(0);
    BARRIER();

    readA(la0, 1);
    if (sA1) stageA(t2 + 1, 1);
    BARRIER();
    MF(1);
    BARRIER();

    readA(la0, 2);
    if (sN) stageB(t2 + 2, 0);
    BARRIER();
    MF(2);
    BARRIER();

    readA(la0, 3);
    if (sN) stageB(t2 + 2, 1);
    BARRIER();
    MF(3);
    if (sN) { WAITV(4); } else { WAITV(0); }
    BARRIER();

    // ---------- tile t2+1 (dbuf 1) ----------
    readB(lb1); readA(la1, 0);
    if (sN) stageA(t2 + 2, 0);
    BARRIER();
    MF(0);
    BARRIER();

    readA(la1, 1);
    if (sN) stageA(t2 + 2, 1);
    BARRIER();
    MF(1);
    BARRIER();

    readA(la1, 2);
    if (sN) stageB(t2 + 3, 0);
    BARRIER();
    MF(2);
    BARRIER();

    readA(la1, 3);
    if (sN) stageB(t2 + 3, 1);
    BARRIER();
    MF(3);
    if (sN) { WAITV(4); } else { WAITV(0); }
    BARRIER();
  }

#pragma unroll
  for (int ni = 0; ni < 4; ++ni) {
    const int col = bn + wc * 64 + ni * 16 + r;
    const float bv = bias[col];
#pragma unroll
    for (int mi = 0; mi < 8; ++mi) {
      const int row0 = bm + wr * 128 + mi * 16 + (g << 2);
#pragma unroll
      for (int j = 0; j < 4; ++j) {
        float v = acc[mi][ni][j] + bv;
        if (OUT_BF16)
          ((unsigned short*)Cp)[(size_t)(row0 + j) * ldc + col] = f2bf(v);
        else
          ((float*)Cp)[(size_t)(row0 + j) * ldc + col] = v;
      }
    }
  }
}

// ---------------------------------------------------------------------------
// Per-token head-vs-head attention (16x16 per token), fp32 math.
__global__ __launch_bounds__(256) void attn_kernel(
    const unsigned short* __restrict__ out1, const unsigned short* __restrict__ kv,
    unsigned short* __restrict__ aout) {
  const int o = blockIdx.x;
  const int s = (o & 7) * 2048 + (o >> 3);
  const int t = threadIdx.x;
  __shared__ float qs[16 * 132], ks2[16 * 132], vs[16 * 132];
  __shared__ float attn[256];
  const int h = t >> 4, d0 = (t & 15) * 8;

  union U8 { uint4v v; unsigned short us[8]; };
  U8 qv, kv8, vv;
  qv.v = *(const uint4v*)(out1 + (size_t)s * 3072 + 1024 + t * 8);
  kv8.v = *(const uint4v*)(kv + (size_t)s * 4096 + t * 8);
  vv.v = *(const uint4v*)(kv + (size_t)s * 4096 + 2048 + t * 8);
#pragma unroll
  for (int j = 0; j < 8; ++j) {
    qs[h * 132 + d0 + j] = bf2f(qv.us[j]);
    ks2[h * 132 + d0 + j] = bf2f(kv8.us[j]);
    vs[h * 132 + d0 + j] = bf2f(vv.us[j]);
  }
  __syncthreads();

  const int gg0 = t & 15;
  const f32x4* qrow = (const f32x4*)&qs[h * 132];
  const f32x4* krow = (const f32x4*)&ks2[gg0 * 132];
  float acc = 0.f;
#pragma unroll
  for (int dd = 0; dd < 32; ++dd) {
    f32x4 a4 = qrow[dd], b4 = krow[dd];
    acc += a4.x * b4.x + a4.y * b4.y + a4.z * b4.z + a4.w * b4.w;
  }
  acc *= 0.08838834764831845f;
  float mx = acc;
#pragma unroll
  for (int ofs = 8; ofs; ofs >>= 1) mx = fmaxf(mx, __shfl_xor(mx, ofs));
  float e = __expf(acc - mx);
  float sm = e;
#pragma unroll
  for (int ofs = 8; ofs; ofs >>= 1) sm += __shfl_xor(sm, ofs);
  attn[t] = e / sm;
  __syncthreads();

  f32x4 o0 = (f32x4){0.f, 0.f, 0.f, 0.f}, o1 = (f32x4){0.f, 0.f, 0.f, 0.f};
#pragma unroll
  for (int gg = 0; gg < 16; ++gg) {
    const float a = attn[(h << 4) + gg];
    f32x4 v0 = *(const f32x4*)&vs[gg * 132 + d0];
    f32x4 v1 = *(const f32x4*)&vs[gg * 132 + d0 + 4];
    o0 += v0 * a;
    o1 += v1 * a;
  }
  U8 ov;
  ov.us[0] = f2bf(o0.x); ov.us[1] = f2bf(o0.y); ov.us[2] = f2bf(o0.z); ov.us[3] = f2bf(o0.w);
  ov.us[4] = f2bf(o1.x); ov.us[5] = f2bf(o1.y); ov.us[6] = f2bf(o1.z); ov.us[7] = f2bf(o1.w);
  *(uint4v*)(aout + (size_t)s * 2048 + t * 8) = ov.v;
}

// ---------------------------------------------------------------------------
extern "C" void kernel_launch(void* const* d_in, const int* in_sizes, int n_in,
                              void* d_out, int out_size, void* d_ws, size_t ws_size,
                              hipStream_t stream) {
  (void)in_sizes; (void)n_in; (void)out_size; (void)ws_size;
  const float* x    = (const float*)d_in[0];
  const float* Wd_k = (const float*)d_in[1];
  const float* bd_k = (const float*)d_in[2];
  const float* Wu_k = (const float*)d_in[3];
  const float* bu_k = (const float*)d_in[4];
  const float* Wd_v = (const float*)d_in[5];
  const float* bd_v = (const float*)d_in[6];
  const float* Wu_v = (const float*)d_in[7];
  const float* bu_v = (const float*)d_in[8];
  const float* Wq   = (const float*)d_in[9];
  const float* bq   = (const float*)d_in[10];
  const float* Wo   = (const float*)d_in[11];
  const float* bo   = (const float*)d_in[12];

  char* ws = (char*)d_ws;
  unsigned short* w1t  = (unsigned short*)(ws);             // [3072][2048] bf16
  unsigned short* w2t  = (unsigned short*)(ws + 12582912);  // [4096][512]  bf16
  unsigned short* w3t  = (unsigned short*)(ws + 16777216);  // [2048][2048] bf16
  float*          b1   = (float*)(ws + 25165824);           // [3072]
  float*          b2   = (float*)(ws + 25178112);           // [4096]
  unsigned short* xb   = (unsigned short*)(ws + 25194496);  // [16384][2048] bf16
  unsigned short* out1 = (unsigned short*)(ws + 92303360);  // [16384][3072] bf16
  unsigned short* kvb  = (unsigned short*)(ws + 192966656); // [16384][4096] bf16
  unsigned short* attO = xb;  // reuse xb after GEMM1

  dim3 blk(256);

  prep_kernel<<<dim3(28700), blk, 0, stream>>>(
      x, Wq, Wo, Wd_k, Wd_v, Wu_k, Wu_v, bd_k, bd_v, bq, bu_k, bu_v,
      w1t, w2t, w3t, b1, b2, xb);

  // GEMM1: [16384,2048]@[2048,3072] -> out1 (cache_k|cache_v|q); 64x12 tiles
  gemm_bt<1><<<dim3(64 * 12), dim3(512), 0, stream>>>(
      xb, 2048, 1 << 30, 0, w1t, 2048, b1, out1, 3072, 2048, 12);

  // GEMM2 fused: k|v = [cache_k|cache_v]@blockdiag(Wu_k,Wu_v) -> kvb; 64x16
  gemm_bt<1><<<dim3(64 * 16), dim3(512), 0, stream>>>(
      out1, 3072, 2048, 512, w2t, 512, b2, kvb, 4096, 512, 16);

  // per-token attention (XCD-aligned token order)
  attn_kernel<<<dim3(16384), blk, 0, stream>>>(out1, kvb, attO);

  // GEMM3: attO@Wo + bo -> d_out fp32; 64x8 tiles
  gemm_bt<0><<<dim3(64 * 8), dim3(512), 0, stream>>>(
      attO, 2048, 1 << 30, 0, w3t, 2048, bo, (float*)d_out, 2048, 2048, 8);
}

// Round 17
// 561.827 us; speedup vs baseline: 1.0136x; 1.0136x over previous
//
#include <hip/hip_runtime.h>

typedef __attribute__((ext_vector_type(8))) short short8v;
typedef __attribute__((ext_vector_type(4))) float f32x4;
typedef __attribute__((ext_vector_type(4))) unsigned int uint4v;

#define GLOBAL_AS(p) ((const __attribute__((address_space(1))) void*)(p))
#define LDS_AS(p)    ((__attribute__((address_space(3))) void*)(p))
#define WAITV(n) asm volatile("s_waitcnt vmcnt(" #n ")" ::: "memory")
#define BARRIER() __builtin_amdgcn_s_barrier()

__device__ __forceinline__ unsigned short f2bf(float f) {
  unsigned int u = __builtin_bit_cast(unsigned int, f);
  u += 0x7fffu + ((u >> 16) & 1u);
  return (unsigned short)(u >> 16);
}
__device__ __forceinline__ float bf2f(unsigned short u) {
  unsigned int x = ((unsigned int)u) << 16;
  return __builtin_bit_cast(float, x);
}

// ---------------------------------------------------------------------------
// Merged prep: [0,12288) weight transposes fp32[K,N]->bf16[N,K];
// [12288,12316) bias concat; [12316,28700) x fp32->bf16 (XCD-aligned rows).
__global__ __launch_bounds__(256) void prep_kernel(
    const float* __restrict__ x,
    const float* __restrict__ Wq, const float* __restrict__ Wo,
    const float* __restrict__ Wd_k, const float* __restrict__ Wd_v,
    const float* __restrict__ Wu_k, const float* __restrict__ Wu_v,
    const float* __restrict__ bd_k, const float* __restrict__ bd_v,
    const float* __restrict__ bq, const float* __restrict__ bu_k,
    const float* __restrict__ bu_v,
    unsigned short* __restrict__ w1t, unsigned short* __restrict__ w2t,
    unsigned short* __restrict__ w3t, float* __restrict__ b1,
    float* __restrict__ b2, unsigned short* __restrict__ xb) {
  int b = blockIdx.x;
  if (b >= 12316) {  // ---- x fp32 -> bf16
    const int o = b - 12316;
    const size_t row = (size_t)((o & 7) * 2048 + (o >> 3));
    size_t i = row * 2048 + threadIdx.x * 8;
    f32x4 v0 = *(const f32x4*)(x + i);
    f32x4 v1 = *(const f32x4*)(x + i + 4);
    union U8 { uint4v v; unsigned short us[8]; } o8;
    o8.us[0] = f2bf(v0.x); o8.us[1] = f2bf(v0.y); o8.us[2] = f2bf(v0.z); o8.us[3] = f2bf(v0.w);
    o8.us[4] = f2bf(v1.x); o8.us[5] = f2bf(v1.y); o8.us[6] = f2bf(v1.z); o8.us[7] = f2bf(v1.w);
    *(uint4v*)(xb + i) = o8.v;
    return;
  }
  if (b >= 12288) {  // ---- bias concat
    int i = (b - 12288) * 256 + threadIdx.x;
    if (i < 512) b1[i] = bd_k[i];
    else if (i < 1024) b1[i] = bd_v[i - 512];
    else if (i < 3072) b1[i] = bq[i - 1024];
    else if (i < 5120) b2[i - 3072] = bu_k[i - 3072];
    else if (i < 7168) b2[i - 3072] = bu_v[i - 5120];
    return;
  }
  // ---- weight transpose (verified 32x32 LDS-bounce)
  const float* src; unsigned short* dst; int K, N, ntx;
  if (b < 4096)      { src = Wq;   dst = w1t + 1024 * 2048; K = 2048; N = 2048; ntx = 64; }
  else if (b < 8192) { src = Wo;   dst = w3t;               K = 2048; N = 2048; ntx = 64; b -= 4096; }
  else if (b < 9216) { src = Wd_k; dst = w1t;               K = 2048; N = 512;  ntx = 16; b -= 8192; }
  else if (b < 10240){ src = Wd_v; dst = w1t + 512 * 2048;  K = 2048; N = 512;  ntx = 16; b -= 9216; }
  else if (b < 11264){ src = Wu_k; dst = w2t;               K = 512;  N = 2048; ntx = 64; b -= 10240; }
  else               { src = Wu_v; dst = w2t + 2048 * 512;  K = 512;  N = 2048; ntx = 64; b -= 11264; }
  __shared__ float tile[32][33];
  const int bx = b % ntx, by = b / ntx;
  const int tx = threadIdx.x & 31, ty = threadIdx.x >> 5;
  const int k0 = by * 32, n0 = bx * 32;
#pragma unroll
  for (int i = 0; i < 32; i += 8)
    tile[ty + i][tx] = src[(size_t)(k0 + ty + i) * N + n0 + tx];
  __syncthreads();
#pragma unroll
  for (int i = 0; i < 32; i += 8)
    dst[(size_t)(n0 + ty + i) * K + k0 + tx] = f2bf(tile[tx][ty + i]);
}

// ---------------------------------------------------------------------------
// 256x128x64 bf16 GEMM block, 4 waves (2Mx2N), per-wave 128x64, 16x16x32 MFMA.
// R12 structure (best measured: 47% MfmaUtil, ~85% of the 55% LDS-BW ceiling
// for the 128x64-wave-tile class): A (HBM-cold) double-buffered with a
// full-tile prefetch lead; B (weights, L2-hot ~200cy) single-buffered.
// LDS = 2x32K + 16K = 80KB -> 2 blocks/CU, anti-phased barrier domains hide
// B's short stall. Counted WAITV(8): steady outstanding 20; drain 12, keep
// A(T+1)'s 8 flying. XOR-swizzled LDS via pre-swizzled global source.
template <int OUT_BF16>
__global__ __launch_bounds__(256, 2) void gemm_bt(
    const unsigned short* __restrict__ A, int lda, int nsplit_col, int acol_off,
    const unsigned short* __restrict__ Bt, int ldb,
    const float* __restrict__ bias, void* __restrict__ Cp, int ldc,
    int K, int ntn) {
  __shared__ unsigned short Als[2][256 * 64];  // 2 x 32KB
  __shared__ unsigned short Bls[128 * 64];     // 16KB
  const int t = threadIdx.x;
  const int lane = t & 63, wave = t >> 6;

  // bijective XCD swizzle (grids here are multiples of 8)
  const int qx = gridDim.x >> 3;
  const int bid = (blockIdx.x & 7) * qx + (blockIdx.x >> 3);
  const int bm = (bid / ntn) * 256;
  const int bn = (bid % ntn) * 128;
  const unsigned short* Ab = A + (bn >= nsplit_col ? acol_off : 0);

  const int wr = wave >> 1, wc = wave & 1;
  const int g = lane >> 4, r = lane & 15;
  const int swz = r & 7;
  const int NT = K >> 6;

  f32x4 acc[8][4];
#pragma unroll
  for (int i = 0; i < 8; ++i)
#pragma unroll
    for (int j = 0; j < 4; ++j) acc[i][j] = (f32x4){0.f, 0.f, 0.f, 0.f};

  // staging: one issue = 32 rows x 64 cols (256 thr x 16B); thread t ->
  // row t>>3, source chunk inverse-XOR-swizzled (linear LDS dest).
  const int srow = t >> 3;
  const int jsrc = (t & 7) ^ (srow & 7);
  const unsigned short* aptr = Ab + (size_t)(bm + srow) * lda + (jsrc << 3);
  const unsigned short* bptr = Bt + (size_t)(bn + srow) * ldb + (jsrc << 3);
  const int wbase = wave * 512;  // wave-uniform LDS dest base (elems)

  auto stageA = [&](int kt, int buf) {
    const unsigned short* ak = aptr + (size_t)kt * 64;
#pragma unroll
    for (int u = 0; u < 8; ++u)
      __builtin_amdgcn_global_load_lds(GLOBAL_AS(ak + (size_t)(u * 32) * lda),
                                       LDS_AS(&Als[buf][u * 2048 + wbase]), 16, 0, 0);
  };
  auto stageB = [&](int kt) {
    const unsigned short* bk = bptr + (size_t)kt * 64;
#pragma unroll
    for (int u = 0; u < 4; ++u)
      __builtin_amdgcn_global_load_lds(GLOBAL_AS(bk + (size_t)(u * 32) * ldb),
                                       LDS_AS(&Bls[u * 2048 + wbase]), 16, 0, 0);
  };

  // prologue: A(0), B(0), A(1) in flight (20 issues)
  stageA(0, 0);
  stageB(0);
  if (NT > 1) stageA(1, 1);

  for (int T = 0; T < NT; ++T) {
    if (T + 1 < NT) { WAITV(8); } else { WAITV(0); }
    BARRIER();
    const unsigned short* la = Als[T & 1];
#pragma unroll
    for (int ks = 0; ks < 2; ++ks) {
      const int c16 = (((ks << 2) + g) ^ swz) << 3;
      short8v bf[4];
#pragma unroll
      for (int ni = 0; ni < 4; ++ni)
        bf[ni] = *(const short8v*)&Bls[(wc * 64 + ni * 16 + r) * 64 + c16];
      __builtin_amdgcn_s_setprio(1);
#pragma unroll
      for (int mi = 0; mi < 8; ++mi) {
        short8v af = *(const short8v*)&la[(wr * 128 + mi * 16 + r) * 64 + c16];
#pragma unroll
        for (int ni = 0; ni < 4; ++ni)
          acc[mi][ni] = __builtin_amdgcn_mfma_f32_16x16x32_bf16(
              af, bf[ni], acc[mi][ni], 0, 0, 0);
      }
      __builtin_amdgcn_s_setprio(0);
    }
    BARRIER();  // all reads done before restaging Bls / Als[T&1]
    if (T + 1 < NT) {
      stageB(T + 1);
      if (T + 2 < NT) stageA(T + 2, T & 1);
    }
  }

#pragma unroll
  for (int ni = 0; ni < 4; ++ni) {
    const int col = bn + wc * 64 + ni * 16 + r;
    const float bv = bias[col];
#pragma unroll
    for (int mi = 0; mi < 8; ++mi) {
      const int row0 = bm + wr * 128 + mi * 16 + (g << 2);
#pragma unroll
      for (int j = 0; j < 4; ++j) {
        float v = acc[mi][ni][j] + bv;
        if (OUT_BF16)
          ((unsigned short*)Cp)[(size_t)(row0 + j) * ldc + col] = f2bf(v);
        else
          ((float*)Cp)[(size_t)(row0 + j) * ldc + col] = v;
      }
    }
  }
}

// ---------------------------------------------------------------------------
// Per-token head-vs-head attention (16x16 per token), fp32 math.
// Block o -> token (o&7)*2048 + (o>>3): XCD-aligned with the GEMM tiles.
__global__ __launch_bounds__(256) void attn_kernel(
    const unsigned short* __restrict__ out1, const unsigned short* __restrict__ kv,
    unsigned short* __restrict__ aout) {
  const int o = blockIdx.x;
  const int s = (o & 7) * 2048 + (o >> 3);
  const int t = threadIdx.x;
  __shared__ float qs[16 * 132], ks2[16 * 132], vs[16 * 132];
  __shared__ float attn[256];
  const int h = t >> 4, d0 = (t & 15) * 8;

  union U8 { uint4v v; unsigned short us[8]; };
  U8 qv, kv8, vv;
  qv.v = *(const uint4v*)(out1 + (size_t)s * 3072 + 1024 + t * 8);
  kv8.v = *(const uint4v*)(kv + (size_t)s * 4096 + t * 8);
  vv.v = *(const uint4v*)(kv + (size_t)s * 4096 + 2048 + t * 8);
#pragma unroll
  for (int j = 0; j < 8; ++j) {
    qs[h * 132 + d0 + j] = bf2f(qv.us[j]);
    ks2[h * 132 + d0 + j] = bf2f(kv8.us[j]);
    vs[h * 132 + d0 + j] = bf2f(vv.us[j]);
  }
  __syncthreads();

  const int gg0 = t & 15;
  const f32x4* qrow = (const f32x4*)&qs[h * 132];
  const f32x4* krow = (const f32x4*)&ks2[gg0 * 132];
  float acc = 0.f;
#pragma unroll
  for (int dd = 0; dd < 32; ++dd) {
    f32x4 a4 = qrow[dd], b4 = krow[dd];
    acc += a4.x * b4.x + a4.y * b4.y + a4.z * b4.z + a4.w * b4.w;
  }
  acc *= 0.08838834764831845f;
  float mx = acc;
#pragma unroll
  for (int ofs = 8; ofs; ofs >>= 1) mx = fmaxf(mx, __shfl_xor(mx, ofs));
  float e = __expf(acc - mx);
  float sm = e;
#pragma unroll
  for (int ofs = 8; ofs; ofs >>= 1) sm += __shfl_xor(sm, ofs);
  attn[t] = e / sm;
  __syncthreads();

  f32x4 o0 = (f32x4){0.f, 0.f, 0.f, 0.f}, o1 = (f32x4){0.f, 0.f, 0.f, 0.f};
#pragma unroll
  for (int gg = 0; gg < 16; ++gg) {
    const float a = attn[(h << 4) + gg];
    f32x4 v0 = *(const f32x4*)&vs[gg * 132 + d0];
    f32x4 v1 = *(const f32x4*)&vs[gg * 132 + d0 + 4];
    o0 += v0 * a;
    o1 += v1 * a;
  }
  U8 ov;
  ov.us[0] = f2bf(o0.x); ov.us[1] = f2bf(o0.y); ov.us[2] = f2bf(o0.z); ov.us[3] = f2bf(o0.w);
  ov.us[4] = f2bf(o1.x); ov.us[5] = f2bf(o1.y); ov.us[6] = f2bf(o1.z); ov.us[7] = f2bf(o1.w);
  *(uint4v*)(aout + (size_t)s * 2048 + t * 8) = ov.v;
}

// ---------------------------------------------------------------------------
extern "C" void kernel_launch(void* const* d_in, const int* in_sizes, int n_in,
                              void* d_out, int out_size, void* d_ws, size_t ws_size,
                              hipStream_t stream) {
  (void)in_sizes; (void)n_in; (void)out_size; (void)ws_size;
  const float* x    = (const float*)d_in[0];
  const float* Wd_k = (const float*)d_in[1];
  const float* bd_k = (const float*)d_in[2];
  const float* Wu_k = (const float*)d_in[3];
  const float* bu_k = (const float*)d_in[4];
  const float* Wd_v = (const float*)d_in[5];
  const float* bd_v = (const float*)d_in[6];
  const float* Wu_v = (const float*)d_in[7];
  const float* bu_v = (const float*)d_in[8];
  const float* Wq   = (const float*)d_in[9];
  const float* bq   = (const float*)d_in[10];
  const float* Wo   = (const float*)d_in[11];
  const float* bo   = (const float*)d_in[12];

  char* ws = (char*)d_ws;
  unsigned short* w1t  = (unsigned short*)(ws);             // [3072][2048] bf16
  unsigned short* w2t  = (unsigned short*)(ws + 12582912);  // [4096][512]  bf16
  unsigned short* w3t  = (unsigned short*)(ws + 16777216);  // [2048][2048] bf16
  float*          b1   = (float*)(ws + 25165824);           // [3072]
  float*          b2   = (float*)(ws + 25178112);           // [4096]
  unsigned short* xb   = (unsigned short*)(ws + 25194496);  // [16384][2048] bf16
  unsigned short* out1 = (unsigned short*)(ws + 92303360);  // [16384][3072] bf16
  unsigned short* kvb  = (unsigned short*)(ws + 192966656); // [16384][4096] bf16
  unsigned short* attO = xb;  // reuse xb after GEMM1

  dim3 blk(256);

  // merged prep: weight transposes + bias concat + x->bf16 (one launch)
  prep_kernel<<<dim3(28700), blk, 0, stream>>>(
      x, Wq, Wo, Wd_k, Wd_v, Wu_k, Wu_v, bd_k, bd_v, bq, bu_k, bu_v,
      w1t, w2t, w3t, b1, b2, xb);

  // GEMM1: [16384,2048]@[2048,3072] -> out1 (cache_k|cache_v|q); 64x24 tiles
  gemm_bt<1><<<dim3(64 * 24), blk, 0, stream>>>(
      xb, 2048, 1 << 30, 0, w1t, 2048, b1, out1, 3072, 2048, 24);

  // GEMM2 fused: k|v = [cache_k|cache_v]@blockdiag(Wu_k,Wu_v) -> kvb; 64x32
  gemm_bt<1><<<dim3(64 * 32), blk, 0, stream>>>(
      out1, 3072, 2048, 512, w2t, 512, b2, kvb, 4096, 512, 32);

  // per-token attention (XCD-aligned token order)
  attn_kernel<<<dim3(16384), blk, 0, stream>>>(out1, kvb, attO);

  // GEMM3: attO@Wo + bo -> d_out fp32; 64x16
  gemm_bt<0><<<dim3(64 * 16), blk, 0, stream>>>(
      attO, 2048, 1 << 30, 0, w3t, 2048, bo, (float*)d_out, 2048, 2048, 16);
}